// Round 3
// baseline (7593.906 us; speedup 1.0000x reference)
//
#include <hip/hip_runtime.h>
#include <hip/hip_bf16.h>

#define NRR 1024
#define NCC 1024
#define NN (NRR*NCC)
#define LHOR (NRR*(NCC-1))   // 1024*1023 horizontal links come first

// model constants
#define OPENING_COEFF 1.3455e-09f
#define CLOSURE_COEFF 7.11e-24f
#define FLOW_COEFF    0.0405f
#define STEP_HEIGHT   0.03f
#define SCALE_CUTOFF  5.74f
#define SEC_PER_A     31556926.0f
#define DT            3600.0f
#define CG_TOL2       1e-6f          // tol^2
#define SCALE_A       1e-4f          // face_w/(len*area) = 100/(100*1e4)
#define SCALE_B       0.01f          // face_w/area       = 100/1e4

// scalar workspace layout: sc[0..64] = gammas, sc[65..128] = pAps
#define SC_GAMMA 0
#define SC_PAP   65

__device__ __forceinline__ bool bnd(int r, int c){
  return (r==0) | (r==NRR-1) | (c==0) | (c==NCC-1);
}

__device__ __forceinline__ void block_reduce_atomic(float v, float* dst){
  #pragma unroll
  for(int off=32; off>0; off>>=1) v += __shfl_down(v, off, 64);
  __shared__ float s[4];
  int lane = threadIdx.x & 63, w = threadIdx.x >> 6;
  if(lane==0) s[w]=v;
  __syncthreads();
  if(threadIdx.x==0) atomicAdd(dst, s[0]+s[1]+s[2]+s[3]);
}

__global__ void k_init(float* sc){
  int i = threadIdx.x;
  if(i < 129) sc[i] = 0.f;
}

// g = (Q * 0.0405 * S^1.25)^2  -> stored in Ap buffer (free until first spmv)
__global__ void k_g(const float* __restrict__ S,
                    const float* __restrict__ Q,
                    float* __restrict__ g){
  int n = blockIdx.x*blockDim.x + threadIdx.x;
  float s = S[n], q = Q[n];
  float t = q * FLOW_COEFF * powf(s, 1.25f);
  g[n] = t*t;
}

// b = flux_div(g_link); r0 = p0 = b; x0 = 0; gamma0 = b.b
__global__ void k_rhs(const float* __restrict__ g,
                      const float* __restrict__ geo,
                      float* __restrict__ x, float* __restrict__ r,
                      float* __restrict__ p, float* sc){
  int n = blockIdx.x*blockDim.x + threadIdx.x;
  int row = n >> 10, col = n & (NCC-1);
  float gc = g[n], geoc = geo[n];
  bool bc = bnd(row, col);
  float b = 0.f, f;
  if(col < NCC-1){ // east link, n is tail: +f
    bool ia = bc | bnd(row, col+1);
    f = ia ? 0.5f*(geoc + geo[n+1]) : 0.5f*(gc + g[n+1]);
    b += f;
  }
  if(col > 0){     // west link, n is head: -f
    bool ia = bc | bnd(row, col-1);
    f = ia ? 0.5f*(geoc + geo[n-1]) : 0.5f*(gc + g[n-1]);
    b -= f;
  }
  if(row < NRR-1){ // down link, n is tail: +f
    bool ia = bc | bnd(row+1, col);
    f = ia ? 0.5f*(geoc + geo[n+NCC]) : 0.5f*(gc + g[n+NCC]);
    b += f;
  }
  if(row > 0){     // up link, n is head: -f
    bool ia = bc | bnd(row-1, col);
    f = ia ? 0.5f*(geoc + geo[n-NCC]) : 0.5f*(gc + g[n-NCC]);
    b -= f;
  }
  b *= SCALE_B;
  x[n] = 0.f; r[n] = b; p[n] = b;
  block_reduce_atomic(b*b, &sc[SC_GAMMA]);
}

// Ap = A(p) (5-point graph Laplacian * 1e-4), pAp partial reduction
__global__ void k_spmv(const float* __restrict__ p, float* __restrict__ Ap,
                       float* sc, int k){
  float g0 = sc[SC_GAMMA], gk = sc[SC_GAMMA + k];
  if(!(gk > CG_TOL2 * g0)) return;
  int n = blockIdx.x*blockDim.x + threadIdx.x;
  int row = n >> 10, col = n & (NCC-1);
  float pc = p[n];
  float sum = 0.f, deg = 0.f;
  if(col < NCC-1){ sum += p[n+1];   deg += 1.f; }
  if(col > 0)    { sum += p[n-1];   deg += 1.f; }
  if(row < NRR-1){ sum += p[n+NCC]; deg += 1.f; }
  if(row > 0)    { sum += p[n-NCC]; deg += 1.f; }
  float ap = SCALE_A * (sum - deg*pc);
  Ap[n] = ap;
  block_reduce_atomic(pc*ap, &sc[SC_PAP + k]);
}

// alpha = gamma_k / pAp_k ; x += alpha p ; r -= alpha Ap ; gamma_{k+1} = r.r
__global__ void k_update(float* __restrict__ x, float* __restrict__ r,
                         const float* __restrict__ p, const float* __restrict__ Ap,
                         float* sc, int k){
  float g0 = sc[SC_GAMMA], gk = sc[SC_GAMMA + k];
  if(!(gk > CG_TOL2 * g0)) return;
  float alpha = gk / sc[SC_PAP + k];
  int n = blockIdx.x*blockDim.x + threadIdx.x;
  x[n] += alpha * p[n];
  float rn = r[n] - alpha * Ap[n];
  r[n] = rn;
  block_reduce_atomic(rn*rn, &sc[SC_GAMMA + k + 1]);
}

// beta = gamma_{k+1}/gamma_k ; p = r + beta p
__global__ void k_pup(float* __restrict__ p, const float* __restrict__ r,
                      const float* sc, int k){
  float g0 = sc[SC_GAMMA], gk = sc[SC_GAMMA + k];
  if(!(gk > CG_TOL2 * g0)) return;
  float beta = sc[SC_GAMMA + k + 1] / gk;
  int n = blockIdx.x*blockDim.x + threadIdx.x;
  p[n] = r[n] + beta * p[n];
}

// fused RK4 with frozen potential phi (=x). All stage terms are node-local.
__global__ void k_final(const float* __restrict__ S0a,
                        const float* __restrict__ Qa,
                        const float* __restrict__ geoa,
                        const float* __restrict__ sva,
                        const float* __restrict__ x,
                        float* __restrict__ out){
  int n = blockIdx.x*blockDim.x + threadIdx.x;
  int row = n >> 10, col = n & (NCC-1);
  float S0 = S0a[n], Q = Qa[n], geo = geoa[n], phi = x[n];

  // gap_base = |mean_of_adjacent_links(sv/sec_per_a)| * step_height
  float svs = 0.f, deg = 0.f;
  if(col < NCC-1){ svs += sva[row*(NCC-1) + col    ]; deg += 1.f; }
  if(col > 0)    { svs += sva[row*(NCC-1) + col - 1]; deg += 1.f; }
  if(row < NRR-1){ svs += sva[LHOR + row*NCC + col      ]; deg += 1.f; }
  if(row > 0)    { svs += sva[LHOR + (row-1)*NCC + col  ]; deg += 1.f; }
  float gap_base = fabsf((svs / SEC_PER_A) / deg) * STEP_HEIGHT;

  float pres = geo - phi;
  float closure_base = CLOSURE_COEFF * pres*pres*pres;

  auto roc = [&](float S)->float{
    float t = Q * FLOW_COEFF * powf(S, 1.25f);
    float g = t*t;
    float melt = OPENING_COEFF * Q * g;
    float gap  = gap_base * (1.f - tanhf(S / SCALE_CUTOFF));
    float clos = closure_base * S;
    return melt + gap - clos;
  };

  float k1 = roc(S0);
  float k2 = roc(S0 + 0.5f*DT*k1);
  float k3 = roc(S0 + 0.5f*DT*k2);
  float k4 = roc(S0 + DT*k3);
  out[n] = S0 + (DT/6.f)*(k1 + 2.f*k2 + 2.f*k3 + k4);
}

extern "C" void kernel_launch(void* const* d_in, const int* in_sizes, int n_in,
                              void* d_out, int out_size, void* d_ws, size_t ws_size,
                              hipStream_t stream){
  const float* S0  = (const float*)d_in[0];
  const float* Q   = (const float*)d_in[1];
  const float* GEO = (const float*)d_in[2];
  const float* SV  = (const float*)d_in[3];

  float* ws = (float*)d_ws;
  float* x  = ws;
  float* r  = ws + (size_t)NN;
  float* p  = ws + (size_t)2*NN;
  float* Ap = ws + (size_t)3*NN;
  float* sc = ws + (size_t)4*NN;

  dim3 blk(256), grd(NN/256);
  k_init<<<1, 256, 0, stream>>>(sc);
  k_g  <<<grd, blk, 0, stream>>>(S0, Q, Ap);            // g lives in Ap buffer
  k_rhs<<<grd, blk, 0, stream>>>(Ap, GEO, x, r, p, sc);
  for(int k = 0; k < 64; ++k){
    k_spmv  <<<grd, blk, 0, stream>>>(p, Ap, sc, k);
    k_update<<<grd, blk, 0, stream>>>(x, r, p, Ap, sc, k);
    k_pup   <<<grd, blk, 0, stream>>>(p, r, sc, k);
  }
  k_final<<<grd, blk, 0, stream>>>(S0, Q, GEO, SV, x, (float*)d_out);
}

// Round 4
// 1353.206 us; speedup vs baseline: 5.6118x; 5.6118x over previous
//
#include <hip/hip_runtime.h>
#include <hip/hip_bf16.h>

#define NRR 1024
#define NCC 1024
#define NN (NRR*NCC)
#define LHOR (NRR*(NCC-1))   // 1024*1023 horizontal links come first

// model constants
#define OPENING_COEFF 1.3455e-09f
#define CLOSURE_COEFF 7.11e-24f
#define FLOW_COEFF    0.0405f
#define STEP_HEIGHT   0.03f
#define SCALE_CUTOFF  5.74f
#define SEC_PER_A     31556926.0f
#define DT            3600.0f
#define CG_TOL2       1e-6f          // tol^2
#define SCALE_A       1e-4f          // face_w/(len*area)
#define SCALE_B       0.01f          // face_w/area

// scalar table (lives in d_out's first 66KB): per-quantity, 8 atomic slots
// strided by 16 floats (64B) to avoid same-line serialization.
// gamma_k parts: line k (k=0..64); pAp_k parts: line 65+k (k=0..63).
#define SLOTS 8
#define SCIDX(line, j) (((line)*SLOTS + (j)) * 16)
#define SC_FLOATS ((65 + 64) * SLOTS * 16)   // 16512 floats = 66 KB

__device__ __forceinline__ bool bnd(int r, int c){
  return (r==0) | (r==NRR-1) | (c==0) | (c==NCC-1);
}

__device__ __forceinline__ float sumParts(const float* __restrict__ sc, int line){
  float s = 0.f;
  #pragma unroll
  for(int j=0; j<SLOTS; j++) s += sc[SCIDX(line, j)];
  return s;
}

__device__ __forceinline__ void block_reduce_slot(float v, float* dst){
  #pragma unroll
  for(int off=32; off>0; off>>=1) v += __shfl_down(v, off, 64);
  __shared__ float s[4];
  int lane = threadIdx.x & 63, w = threadIdx.x >> 6;
  if(lane==0) s[w]=v;
  __syncthreads();
  if(threadIdx.x==0) atomicAdd(dst, s[0]+s[1]+s[2]+s[3]);
}

__global__ __launch_bounds__(256) void k_init(float* sc){
  int i = blockIdx.x*256 + threadIdx.x;
  if(i < SC_FLOATS) sc[i] = 0.f;
}

// g = (Q * 0.0405 * S^1.25)^2  -> stored in Ap buffer (free until first spmv)
__global__ __launch_bounds__(256) void k_g(const float* __restrict__ S,
                                           const float* __restrict__ Q,
                                           float* __restrict__ g){
  int gt = blockIdx.x*256 + threadIdx.x;
  float4 s4 = ((const float4*)S)[gt];
  float4 q4 = ((const float4*)Q)[gt];
  float s[4] = {s4.x, s4.y, s4.z, s4.w};
  float q[4] = {q4.x, q4.y, q4.z, q4.w};
  float4 o;
  float* op = (float*)&o;
  #pragma unroll
  for(int j=0;j<4;j++){
    float t = q[j] * FLOW_COEFF * powf(s[j], 1.25f);
    op[j] = t*t;
  }
  ((float4*)g)[gt] = o;
}

// b = flux_div(g_link); r0 = p0 = b; x0 = 0; gamma0 = b.b
__global__ __launch_bounds__(256) void k_rhs(const float* __restrict__ g,
                                             const float* __restrict__ geo,
                                             float* __restrict__ x, float* __restrict__ r,
                                             float* __restrict__ p, float* sc){
  int gt = blockIdx.x*256 + threadIdx.x;      // 0..262143
  int base = gt*4;
  int row = gt >> 8;
  int cb  = (gt & 255) << 2;
  const float4* g4 = (const float4*)g;
  const float4* e4 = (const float4*)geo;
  float4 gc4 = g4[gt], ec4 = e4[gt];
  float4 gu4 = (row>0)     ? g4[gt-256] : make_float4(0,0,0,0);
  float4 gd4 = (row<NRR-1) ? g4[gt+256] : make_float4(0,0,0,0);
  float4 eu4 = (row>0)     ? e4[gt-256] : make_float4(0,0,0,0);
  float4 ed4 = (row<NRR-1) ? e4[gt+256] : make_float4(0,0,0,0);
  float gL = (cb>0)       ? g[base-1]   : 0.f;
  float gR = (cb<NCC-4)   ? g[base+4]   : 0.f;
  float eL = (cb>0)       ? geo[base-1] : 0.f;
  float eR = (cb<NCC-4)   ? geo[base+4] : 0.f;
  float gh[6] = {gL, gc4.x, gc4.y, gc4.z, gc4.w, gR};
  float eh[6] = {eL, ec4.x, ec4.y, ec4.z, ec4.w, eR};
  float gu[4] = {gu4.x,gu4.y,gu4.z,gu4.w}, gd[4]={gd4.x,gd4.y,gd4.z,gd4.w};
  float eu[4] = {eu4.x,eu4.y,eu4.z,eu4.w}, ed[4]={ed4.x,ed4.y,ed4.z,ed4.w};
  float4 bv; float* bp = (float*)&bv;
  float t_bb = 0.f;
  #pragma unroll
  for(int j=0;j<4;j++){
    int col = cb + j;
    bool bc = bnd(row, col);
    float gcj = gh[j+1], ecj = eh[j+1];
    float b = 0.f, f;
    if(col < NCC-1){  // east, +
      bool ia = bc | bnd(row, col+1);
      f = ia ? 0.5f*(ecj + eh[j+2]) : 0.5f*(gcj + gh[j+2]);
      b += f;
    }
    if(col > 0){      // west, -
      bool ia = bc | bnd(row, col-1);
      f = ia ? 0.5f*(ecj + eh[j]) : 0.5f*(gcj + gh[j]);
      b -= f;
    }
    if(row < NRR-1){  // south, +
      bool ia = bc | bnd(row+1, col);
      f = ia ? 0.5f*(ecj + ed[j]) : 0.5f*(gcj + gd[j]);
      b += f;
    }
    if(row > 0){      // north, -
      bool ia = bc | bnd(row-1, col);
      f = ia ? 0.5f*(ecj + eu[j]) : 0.5f*(gcj + gu[j]);
      b -= f;
    }
    b *= SCALE_B;
    bp[j] = b;
    t_bb += b*b;
  }
  ((float4*)x)[gt] = make_float4(0,0,0,0);
  ((float4*)r)[gt] = bv;
  ((float4*)p)[gt] = bv;
  block_reduce_slot(t_bb, &sc[SCIDX(0, blockIdx.x & (SLOTS-1))]);
}

// Ap = A(p), pAp partial into 8 slots
__global__ __launch_bounds__(256) void k_spmv(const float* __restrict__ p, float* __restrict__ Ap,
                                              float* sc, int k){
  float g0 = sumParts(sc, 0), gk = sumParts(sc, k);
  if(!(gk > CG_TOL2 * g0)) return;
  int gt = blockIdx.x*256 + threadIdx.x;
  int base = gt*4;
  int row = gt >> 8;
  int cb  = (gt & 255) << 2;
  const float4* p4 = (const float4*)p;
  float4 c = p4[gt];
  float4 up = (row>0)     ? p4[gt-256] : make_float4(0,0,0,0);
  float4 dn = (row<NRR-1) ? p4[gt+256] : make_float4(0,0,0,0);
  float pL = (cb>0)     ? p[base-1] : 0.f;
  float pR = (cb<NCC-4) ? p[base+4] : 0.f;
  float ph[6] = {pL, c.x, c.y, c.z, c.w, pR};
  float pu[4] = {up.x,up.y,up.z,up.w}, pd[4]={dn.x,dn.y,dn.z,dn.w};
  float4 apv; float* ap = (float*)&apv;
  float t_pAp = 0.f;
  #pragma unroll
  for(int j=0;j<4;j++){
    int col = cb + j;
    float pcj = ph[j+1];
    float sum = 0.f, deg = 0.f;
    if(col>0)      { sum += ph[j];   deg+=1.f; }
    if(col<NCC-1)  { sum += ph[j+2]; deg+=1.f; }
    if(row>0)      { sum += pu[j];   deg+=1.f; }
    if(row<NRR-1)  { sum += pd[j];   deg+=1.f; }
    float a = SCALE_A*(sum - deg*pcj);
    ap[j] = a;
    t_pAp += pcj*a;
  }
  ((float4*)Ap)[gt] = apv;
  block_reduce_slot(t_pAp, &sc[SCIDX(65 + k, blockIdx.x & (SLOTS-1))]);
}

// alpha = gamma_k/pAp_k ; x += alpha p ; r -= alpha Ap ; gamma_{k+1} = r.r
__global__ __launch_bounds__(256) void k_update(float* __restrict__ x, float* __restrict__ r,
                                                const float* __restrict__ p, const float* __restrict__ Ap,
                                                float* sc, int k){
  float g0 = sumParts(sc, 0), gk = sumParts(sc, k);
  if(!(gk > CG_TOL2 * g0)) return;
  float alpha = gk / sumParts(sc, 65 + k);
  int gt = blockIdx.x*256 + threadIdx.x;
  float4 xv = ((float4*)x)[gt];
  float4 pv = ((const float4*)p)[gt];
  float4 rv = ((float4*)r)[gt];
  float4 av = ((const float4*)Ap)[gt];
  xv.x += alpha*pv.x; xv.y += alpha*pv.y; xv.z += alpha*pv.z; xv.w += alpha*pv.w;
  rv.x -= alpha*av.x; rv.y -= alpha*av.y; rv.z -= alpha*av.z; rv.w -= alpha*av.w;
  ((float4*)x)[gt] = xv;
  ((float4*)r)[gt] = rv;
  float t_rr = rv.x*rv.x + rv.y*rv.y + rv.z*rv.z + rv.w*rv.w;
  block_reduce_slot(t_rr, &sc[SCIDX(k+1, blockIdx.x & (SLOTS-1))]);
}

// beta = gamma_{k+1}/gamma_k ; p = r + beta p
__global__ __launch_bounds__(256) void k_pup(float* __restrict__ p, const float* __restrict__ r,
                                             const float* sc, int k){
  float g0 = sumParts(sc, 0), gk = sumParts(sc, k);
  if(!(gk > CG_TOL2 * g0)) return;
  float beta = sumParts(sc, k+1) / gk;
  int gt = blockIdx.x*256 + threadIdx.x;
  float4 rv = ((const float4*)r)[gt];
  float4 pv = ((float4*)p)[gt];
  pv.x = rv.x + beta*pv.x; pv.y = rv.y + beta*pv.y;
  pv.z = rv.z + beta*pv.z; pv.w = rv.w + beta*pv.w;
  ((float4*)p)[gt] = pv;
}

// fused RK4 with frozen potential phi (=x). All stage terms are node-local.
__global__ __launch_bounds__(256) void k_final(const float* __restrict__ S0a,
                        const float* __restrict__ Qa,
                        const float* __restrict__ geoa,
                        const float* __restrict__ sva,
                        const float* __restrict__ x,
                        float* __restrict__ out){
  int n = blockIdx.x*blockDim.x + threadIdx.x;
  int row = n >> 10, col = n & (NCC-1);
  float S0 = S0a[n], Q = Qa[n], geo = geoa[n], phi = x[n];

  float svs = 0.f, deg = 0.f;
  if(col < NCC-1){ svs += sva[row*(NCC-1) + col    ]; deg += 1.f; }
  if(col > 0)    { svs += sva[row*(NCC-1) + col - 1]; deg += 1.f; }
  if(row < NRR-1){ svs += sva[LHOR + row*NCC + col      ]; deg += 1.f; }
  if(row > 0)    { svs += sva[LHOR + (row-1)*NCC + col  ]; deg += 1.f; }
  float gap_base = fabsf((svs / SEC_PER_A) / deg) * STEP_HEIGHT;

  float pres = geo - phi;
  float closure_base = CLOSURE_COEFF * pres*pres*pres;

  auto roc = [&](float S)->float{
    float t = Q * FLOW_COEFF * powf(S, 1.25f);
    float g = t*t;
    float melt = OPENING_COEFF * Q * g;
    float gap  = gap_base * (1.f - tanhf(S / SCALE_CUTOFF));
    float clos = closure_base * S;
    return melt + gap - clos;
  };

  float k1 = roc(S0);
  float k2 = roc(S0 + 0.5f*DT*k1);
  float k3 = roc(S0 + 0.5f*DT*k2);
  float k4 = roc(S0 + DT*k3);
  out[n] = S0 + (DT/6.f)*(k1 + 2.f*k2 + 2.f*k3 + k4);
}

extern "C" void kernel_launch(void* const* d_in, const int* in_sizes, int n_in,
                              void* d_out, int out_size, void* d_ws, size_t ws_size,
                              hipStream_t stream){
  const float* S0  = (const float*)d_in[0];
  const float* Q   = (const float*)d_in[1];
  const float* GEO = (const float*)d_in[2];
  const float* SV  = (const float*)d_in[3];

  float* ws = (float*)d_ws;
  float* x  = ws;
  float* r  = ws + (size_t)NN;
  float* p  = ws + (size_t)2*NN;
  float* Ap = ws + (size_t)3*NN;
  float* sc = (float*)d_out;   // first 66KB of d_out; k_final overwrites at the end

  dim3 blk(256), grd(NN/4/256);   // 1024 blocks, 4 nodes/thread
  k_init<<<(SC_FLOATS+255)/256, blk, 0, stream>>>(sc);
  k_g  <<<grd, blk, 0, stream>>>(S0, Q, Ap);            // g lives in Ap buffer
  k_rhs<<<grd, blk, 0, stream>>>(Ap, GEO, x, r, p, sc);
  for(int k = 0; k < 64; ++k){
    k_spmv  <<<grd, blk, 0, stream>>>(p, Ap, sc, k);
    k_update<<<grd, blk, 0, stream>>>(x, r, p, Ap, sc, k);
    k_pup   <<<grd, blk, 0, stream>>>(p, r, sc, k);
  }
  k_final<<<NN/256, blk, 0, stream>>>(S0, Q, GEO, SV, x, (float*)d_out);
}